// Round 8
// baseline (387.268 us; speedup 1.0000x reference)
//
#include <hip/hip_runtime.h>
#include <math.h>

// Problem constants (from reference)
constexpr int cS  = 16;   // sequence
constexpr int cB  = 8;    // batch
constexpr int cNC = 5;    // classes
constexpr int cD  = 256;  // hidden
constexpr int cP  = 16;   // patches
constexpr int cPD = 49;   // patch dim
constexpr int cDFT = 128; // channel-mixer hidden
constexpr int cEP  = 64;  // token-mixer hidden (EF*P)
#define LEPS 1e-5f

__device__ __forceinline__ float frcp(float x) { return __builtin_amdgcn_rcpf(x); }
__device__ __forceinline__ float sigm(float x) { return frcp(1.0f + __expf(-x)); }
// gelu(tanh approx) == x * sigmoid(2*0.79788456*(x+0.044715x^3)): 1 exp + rcp
__device__ __forceinline__ float gelu_t(float x) {
  const float z = 1.5957691216057308f * (x + 0.044715f * x * x * x);
  return x * frcp(1.0f + __expf(-z));
}

// ---- DPP 16-lane reductions: 4 dependent VALU ops instead of 4 ds_swizzles
template<int CTRL>
__device__ __forceinline__ float dpp_mov(float v) {
  return __int_as_float(__builtin_amdgcn_update_dpp(
      0, __float_as_int(v), CTRL, 0xF, 0xF, true));
}
__device__ __forceinline__ float row_sum16(float v) {
  v += dpp_mov<0xB1>(v);   // quad_perm [1,0,3,2]
  v += dpp_mov<0x4E>(v);   // quad_perm [2,3,0,1]
  v += dpp_mov<0x124>(v);  // row_ror:4
  v += dpp_mov<0x128>(v);  // row_ror:8
  return v;
}
__device__ __forceinline__ float wave_sum64(float v) {
  v = row_sum16(v);
  v += __shfl_xor(v, 16, 64);
  v += __shfl_xor(v, 32, 64);
  return v;
}

// ---------------- token SRWM (+ fused embed on layer 0) --------------------
// grid = 128 blocks x 256 threads; instance = (b, d); feature axis = patch r.
// we!=0: compute xp[] directly from image+inW (embed) -- embed never hits HBM.
__global__ __launch_bounds__(256) void k_tok_srwm(
    float* __restrict__ h, const float* __restrict__ Wy0, const float* __restrict__ Wq0,
    const float* __restrict__ Wk0, const float* __restrict__ wb0,
    const float* __restrict__ lng, const float* __restrict__ lnb,
    int we, const float* __restrict__ x, const int* __restrict__ fb,
    const float* __restrict__ inW, const float* __restrict__ inb) {
  const int t    = threadIdx.x;
  const int lane = t & 63;
  const int w    = t >> 6;
  const int r    = lane & 15;          // patch index (row of the 16x16 system)
  const int li   = lane >> 4;
  const int b    = blockIdx.x >> 4;
  const int d0   = (blockIdx.x & 15) << 4;
  const int d    = d0 + (w << 2) + li;
  __shared__ float img[784];
  __shared__ float Win[784];           // inW[j][d0..d0+15]
  float wy[16], wq[16], wk[16], wbr[16];
#pragma unroll
  for (int j = 0; j < 16; ++j) {
    wy[j]  = Wy0[r * 16 + j];
    wq[j]  = Wq0[r * 16 + j];
    wk[j]  = Wk0[r * 16 + j];
    wbr[j] = wb0[(r & 3) * 16 + j];
  }
  const float gg = lng[r], bb = lnb[r];
  float xp[16];
  if (we) {
    for (int idx = t; idx < 784; idx += 256)
      Win[idx] = inW[(size_t)(idx >> 4) * cD + d0 + (idx & 15)];
    const int dl = (w << 2) + li;
    const int ph = r >> 2, pw = r & 3;
    const float ib = inb[d];
    for (int s = 0; s < 16; ++s) {
      for (int idx = t; idx < 784; idx += 256)
        img[idx] = x[(size_t)(s * cB + b) * 784 + idx];
      __syncthreads();
      const int cls = fb[s * cB + b];
      float acc = ib + inW[(size_t)(cPD + cls) * cD + d];
#pragma unroll
      for (int j = 0; j < cPD; ++j)
        acc += img[(ph * 7 + j / 7) * 28 + pw * 7 + (j % 7)] * Win[j * 16 + dl];
      xp[s] = acc;
      __syncthreads();
    }
  } else {
#pragma unroll
    for (int s = 0; s < 16; ++s)
      xp[s] = h[((size_t)(s * cB + b) * cP + r) * cD + d];
  }
  for (int s = 0; s < cS; ++s) {
    const float xv = xp[s];
    float y = 0.f, q = 0.f, k = 0.f, bt = 0.f;
#pragma unroll
    for (int j = 0; j < 16; ++j) {
      const float xj = __shfl(xv, j, 16);
      y += wy[j] * xj; q += wq[j] * xj; k += wk[j] * xj; bt += wbr[j] * xj;
    }
    const float bsig = sigm(bt);
    const float eq = __expf(q), ek = __expf(k);
    float ay = 0.f, vyk = 0.f, vqq = 0.f, vqk = 0.f, vkq = 0.f, vkk = 0.f, vbq = 0.f, vbk = 0.f;
    float ksj[16];
#pragma unroll
    for (int j = 0; j < 16; ++j) {
      const float qj = __shfl(eq, j, 16);
      const float kj = __shfl(ek, j, 16);
      ksj[j] = kj;
      ay  += wy[j]  * qj; vyk += wy[j]  * kj;
      vqq += wq[j]  * qj; vqk += wq[j]  * kj;
      vkq += wk[j]  * qj; vkk += wk[j]  * kj;
      vbq += wbr[j] * qj; vbk += wbr[j] * kj;
    }
    const float rq = frcp(row_sum16(eq));
    const float rk = frcp(row_sum16(ek));
    const float ea = __expf(ay * rq);
    const float vyq = ea * frcp(row_sum16(ea));
    const float b0  = __shfl(bsig, 0, 16);
    const float b1v = __shfl(bsig, 1, 16);
    const float b2v = __shfl(bsig, 2, 16);
    const float b3v = __shfl(bsig, 3, 16);
    const float cy = b0  * (vyq      - vyk * rk) * rk;
    const float cq = b1v * (vqq * rq - vqk * rk) * rk;
    const float ck = b2v * (vkq * rq - vkk * rk) * rk;
    const float cb = b3v * (vbq * rq - vbk * rk) * rk;
#pragma unroll
    for (int j = 0; j < 16; ++j) {
      wy[j] += cy * ksj[j]; wq[j] += cq * ksj[j]; wk[j] += ck * ksj[j]; wbr[j] += cb * ksj[j];
    }
    const float s1 = row_sum16(y);
    const float s2 = row_sum16(y * y);
    const float m = s1 * 0.0625f;
    const float var = s2 * 0.0625f - m * m;
    h[((size_t)(s * cB + b) * cP + r) * cD + d] = (y - m) * rsqrtf(var + LEPS) * gg + bb;
  }
}

// ---------------- token mixer: LN(D) then FFN over patch axis --------------
__global__ __launch_bounds__(256) void k_tok_mixer(
    float* __restrict__ h, const float* __restrict__ g, const float* __restrict__ bta,
    const float* __restrict__ W1, const float* __restrict__ b1,
    const float* __restrict__ W2, const float* __restrict__ b2) {
  const int sb = blockIdx.x;
  const int t = threadIdx.x;
  __shared__ float tile[16][256];
  __shared__ float W1s[16 * 64], W2s[64 * 16];
  __shared__ float mean_[16], rstd_[16];
  __shared__ float red[16][17], red2[16][17];
  const size_t base = (size_t)sb * cP * cD;
#pragma unroll
  for (int p = 0; p < 16; ++p) tile[p][t] = h[base + p * 256 + t];
  W1s[t] = W1[t]; W1s[t + 256] = W1[t + 256]; W1s[t + 512] = W1[t + 512]; W1s[t + 768] = W1[t + 768];
  W2s[t] = W2[t]; W2s[t + 256] = W2[t + 256]; W2s[t + 512] = W2[t + 512]; W2s[t + 768] = W2[t + 768];
  __syncthreads();
  const int p = t >> 4, l = t & 15;
  float ps = 0.f, ps2 = 0.f;
#pragma unroll
  for (int k = 0; k < 16; ++k) { const float v = tile[p][l + 16 * k]; ps += v; ps2 += v * v; }
  red[p][l] = ps; red2[p][l] = ps2;
  __syncthreads();
  if (t < 16) {
    float sm = 0.f, s2 = 0.f;
#pragma unroll
    for (int k = 0; k < 16; ++k) { sm += red[t][k]; s2 += red2[t][k]; }
    const float m = sm * (1.f / 256.f);
    mean_[t] = m;
    rstd_[t] = rsqrtf(s2 * (1.f / 256.f) - m * m + LEPS);
  }
  __syncthreads();
  const float gd = g[t], bd = bta[t];
  float v[16], out[16];
#pragma unroll
  for (int pp = 0; pp < 16; ++pp) {
    v[pp] = (tile[pp][t] - mean_[pp]) * rstd_[pp] * gd + bd;
    out[pp] = b2[pp];
  }
  for (int e = 0; e < cEP; ++e) {
    float acc = b1[e];
#pragma unroll
    for (int pp = 0; pp < 16; ++pp) acc += v[pp] * W1s[pp * 64 + e];
    const float ge = gelu_t(acc);
#pragma unroll
    for (int pp = 0; pp < 16; ++pp) out[pp] += ge * W2s[e * 16 + pp];
  }
#pragma unroll
  for (int pp = 0; pp < 16; ++pp) h[base + pp * 256 + t] = tile[pp][t] + out[pp];
}

// ---------------- channel SRWM + FUSED channel mixer -----------------------
__global__ __launch_bounds__(256, 1) void k_ch_srwm_mix(
    float* __restrict__ h, const float* __restrict__ Wy0, const float* __restrict__ Wq0,
    const float* __restrict__ Wk0, const float* __restrict__ wb0,
    const float* __restrict__ lng, const float* __restrict__ lnb,
    const float* __restrict__ mg, const float* __restrict__ mb,
    const float* __restrict__ W1, const float* __restrict__ b1,
    const float* __restrict__ W2, const float* __restrict__ b2) {
  const int t = threadIdx.x;
  const int w = t >> 6;
  const int hh = t >> 4, r = t & 15;
  const int bp = blockIdx.x;
  __shared__ float yout[16][256];
  __shared__ float lnv[8][256];
  __shared__ float hid[8][128];
  __shared__ float pS[2][4], pQ[2][4];
  {
    float wy[16], wq[16], wk[16], wbr[16];
#pragma unroll
    for (int j = 0; j < 16; ++j) {
      wy[j]  = Wy0[(hh * 16 + r) * 16 + j];
      wq[j]  = Wq0[(hh * 16 + r) * 16 + j];
      wk[j]  = Wk0[(hh * 16 + r) * 16 + j];
      wbr[j] = wb0[(hh * 4 + (r & 3)) * 16 + j];
    }
    const float gg = lng[t], bb = lnb[t];
    float xp[16];
#pragma unroll
    for (int s = 0; s < 16; ++s)
      xp[s] = h[(size_t)(s * cB * cP + bp) * cD + t];
    for (int s = 0; s < cS; ++s) {
      const float xv = xp[s];
      float y = 0.f, q = 0.f, k = 0.f, bt = 0.f;
#pragma unroll
      for (int j = 0; j < 16; ++j) {
        const float xj = __shfl(xv, j, 16);
        y += wy[j] * xj; q += wq[j] * xj; k += wk[j] * xj; bt += wbr[j] * xj;
      }
      const float bsig = sigm(bt);
      const float eq = __expf(q), ek = __expf(k);
      float ay = 0.f, vyk = 0.f, vqq = 0.f, vqk = 0.f, vkq = 0.f, vkk = 0.f, vbq = 0.f, vbk = 0.f;
      float ksj[16];
#pragma unroll
      for (int j = 0; j < 16; ++j) {
        const float qj = __shfl(eq, j, 16);
        const float kj = __shfl(ek, j, 16);
        ksj[j] = kj;
        ay  += wy[j]  * qj; vyk += wy[j]  * kj;
        vqq += wq[j]  * qj; vqk += wq[j]  * kj;
        vkq += wk[j]  * qj; vkk += wk[j]  * kj;
        vbq += wbr[j] * qj; vbk += wbr[j] * kj;
      }
      const float rq = frcp(row_sum16(eq));
      const float rk = frcp(row_sum16(ek));
      const float ea = __expf(ay * rq);
      const float vyq = ea * frcp(row_sum16(ea));
      const float b0  = __shfl(bsig, 0, 16);
      const float b1v = __shfl(bsig, 1, 16);
      const float b2v = __shfl(bsig, 2, 16);
      const float b3v = __shfl(bsig, 3, 16);
      const float cy = b0  * (vyq      - vyk * rk) * rk;
      const float cq = b1v * (vqq * rq - vqk * rk) * rk;
      const float ck = b2v * (vkq * rq - vkk * rk) * rk;
      const float cb = b3v * (vbq * rq - vbk * rk) * rk;
#pragma unroll
      for (int j = 0; j < 16; ++j) {
        wy[j] += cy * ksj[j]; wq[j] += cq * ksj[j]; wk[j] += ck * ksj[j]; wbr[j] += cb * ksj[j];
      }
      float s1 = row_sum16(y);
      float s2 = row_sum16(y * y);
      s1 += __shfl_xor(s1, 16, 64); s1 += __shfl_xor(s1, 32, 64);
      s2 += __shfl_xor(s2, 16, 64); s2 += __shfl_xor(s2, 32, 64);
      const int db = s & 1;
      if ((t & 63) == 0) { pS[db][w] = s1; pQ[db][w] = s2; }
      __syncthreads();
      const float sm1 = pS[db][0] + pS[db][1] + pS[db][2] + pS[db][3];
      const float sm2 = pQ[db][0] + pQ[db][1] + pQ[db][2] + pQ[db][3];
      const float m = sm1 * (1.f / 256.f);
      const float var = sm2 * (1.f / 256.f) - m * m;
      yout[s][t] = (y - m) * rsqrtf(var + LEPS) * gg + bb;
    }
  }
  __syncthreads();
  // ---- fused channel mixer over the 16 rows (s) this block owns ----
  {
    const int r32 = t >> 5, l = t & 31;
    const float4 g0 = ((const float4*)mg)[l * 2];
    const float4 g1 = ((const float4*)mg)[l * 2 + 1];
    const float4 q0 = ((const float4*)mb)[l * 2];
    const float4 q1 = ((const float4*)mb)[l * 2 + 1];
    for (int grp = 0; grp < 2; ++grp) {
      const int s = grp * 8 + r32;
      const float4 x0 = ((const float4*)yout[s])[l * 2];
      const float4 x1 = ((const float4*)yout[s])[l * 2 + 1];
      float s1 = x0.x + x0.y + x0.z + x0.w + x1.x + x1.y + x1.z + x1.w;
      float s2 = x0.x * x0.x + x0.y * x0.y + x0.z * x0.z + x0.w * x0.w +
                 x1.x * x1.x + x1.y * x1.y + x1.z * x1.z + x1.w * x1.w;
#pragma unroll
      for (int o = 1; o < 32; o <<= 1) {
        s1 += __shfl_xor(s1, o, 32);
        s2 += __shfl_xor(s2, o, 32);
      }
      const float m = s1 * (1.f / 256.f);
      const float rst = rsqrtf(s2 * (1.f / 256.f) - m * m + LEPS);
      float4 L0, L1;
      L0.x = (x0.x - m) * rst * g0.x + q0.x; L0.y = (x0.y - m) * rst * g0.y + q0.y;
      L0.z = (x0.z - m) * rst * g0.z + q0.z; L0.w = (x0.w - m) * rst * g0.w + q0.w;
      L1.x = (x1.x - m) * rst * g1.x + q1.x; L1.y = (x1.y - m) * rst * g1.y + q1.y;
      L1.z = (x1.z - m) * rst * g1.z + q1.z; L1.w = (x1.w - m) * rst * g1.w + q1.w;
      ((float4*)lnv[r32])[l * 2]     = L0;
      ((float4*)lnv[r32])[l * 2 + 1] = L1;
      __syncthreads();
      {
        // GEMV1 256->128, 4-way split accumulators (chain 256 -> 64)
        const float4* W1f = (const float4*)W1;
        float4 a0 = ((const float4*)b1)[l];
        float4 a1 = {0.f, 0.f, 0.f, 0.f}, a2 = a1, a3 = a1;
        for (int j = 0; j < 256; j += 4) {
          const float xj0 = lnv[r32][j],     xj1 = lnv[r32][j + 1];
          const float xj2 = lnv[r32][j + 2], xj3 = lnv[r32][j + 3];
          const float4 w0 = W1f[(j    ) * 32 + l];
          const float4 w1 = W1f[(j + 1) * 32 + l];
          const float4 w2 = W1f[(j + 2) * 32 + l];
          const float4 w3 = W1f[(j + 3) * 32 + l];
          a0.x += xj0 * w0.x; a0.y += xj0 * w0.y; a0.z += xj0 * w0.z; a0.w += xj0 * w0.w;
          a1.x += xj1 * w1.x; a1.y += xj1 * w1.y; a1.z += xj1 * w1.z; a1.w += xj1 * w1.w;
          a2.x += xj2 * w2.x; a2.y += xj2 * w2.y; a2.z += xj2 * w2.z; a2.w += xj2 * w2.w;
          a3.x += xj3 * w3.x; a3.y += xj3 * w3.y; a3.z += xj3 * w3.z; a3.w += xj3 * w3.w;
        }
        float4 hv;
        hv.x = gelu_t(a0.x + a1.x + a2.x + a3.x);
        hv.y = gelu_t(a0.y + a1.y + a2.y + a3.y);
        hv.z = gelu_t(a0.z + a1.z + a2.z + a3.z);
        hv.w = gelu_t(a0.w + a1.w + a2.w + a3.w);
        ((float4*)hid[r32])[l] = hv;
      }
      __syncthreads();
      {
        // GEMV2 128->256, 2-way split accumulators
        const float4* W2f = (const float4*)W2;
        float4 a0 = ((const float4*)b2)[l * 2];
        float4 a1 = ((const float4*)b2)[l * 2 + 1];
        float4 c0 = {0.f, 0.f, 0.f, 0.f}, c1 = c0;
        for (int e = 0; e < 128; e += 2) {
          const float xh0 = hid[r32][e], xh1 = hid[r32][e + 1];
          const float4 w0 = W2f[(e    ) * 64 + l * 2];
          const float4 w1 = W2f[(e    ) * 64 + l * 2 + 1];
          const float4 w2 = W2f[(e + 1) * 64 + l * 2];
          const float4 w3 = W2f[(e + 1) * 64 + l * 2 + 1];
          a0.x += xh0 * w0.x; a0.y += xh0 * w0.y; a0.z += xh0 * w0.z; a0.w += xh0 * w0.w;
          a1.x += xh0 * w1.x; a1.y += xh0 * w1.y; a1.z += xh0 * w1.z; a1.w += xh0 * w1.w;
          c0.x += xh1 * w2.x; c0.y += xh1 * w2.y; c0.z += xh1 * w2.z; c0.w += xh1 * w2.w;
          c1.x += xh1 * w3.x; c1.y += xh1 * w3.y; c1.z += xh1 * w3.z; c1.w += xh1 * w3.w;
        }
        a0.x += c0.x + x0.x; a0.y += c0.y + x0.y; a0.z += c0.z + x0.z; a0.w += c0.w + x0.w;
        a1.x += c1.x + x1.x; a1.y += c1.y + x1.y; a1.z += c1.z + x1.z; a1.w += c1.w + x1.w;
        float4* op = (float4*)(h + (size_t)(s * cB * cP + bp) * cD);
        op[l * 2]     = a0;
        op[l * 2 + 1] = a1;
      }
      __syncthreads();
    }
  }
}

// ---------------- FUSED: final LN+mean prologue, output SRWM, projection ---
// grid = B = 8 blocks x 256 threads. Projection via linearity:
// sum_t lnt*w = rst*S1c - rst*m*Gc + Bc  (Gc,Bc step-invariant) -> the
// LN-stats and projection partials share ONE barrier per step (was 2), and
// lnt is never materialized.
__global__ __launch_bounds__(256, 1) void k_out_srwm(
    const float* __restrict__ h, float* __restrict__ outp,
    const float* __restrict__ flng, const float* __restrict__ flnb,
    const float* __restrict__ Wy0, const float* __restrict__ Wq0,
    const float* __restrict__ Wk0, const float* __restrict__ wb0,
    const float* __restrict__ lng, const float* __restrict__ lnb,
    const float* __restrict__ outW, const float* __restrict__ outb) {
  const int t = threadIdx.x;
  const int lane = t & 63;
  const int w = t >> 6;
  const int hh = t >> 4, r = t & 15;
  const int b = blockIdx.x;
  __shared__ float gmat[16][256];      // fln+mean output (the SRWM input)
  __shared__ float GBp[4][10];         // per-wave partials of Gc,Bc
  __shared__ float GBs[10];            // block sums
  __shared__ float PR[2][4][7];        // per-step: s1,s2,S1c[5] per wave
  float wy[16], wq[16], wk[16], wbr[16];
#pragma unroll
  for (int j = 0; j < 16; ++j) {
    wy[j]  = Wy0[(hh * 16 + r) * 16 + j];
    wq[j]  = Wq0[(hh * 16 + r) * 16 + j];
    wk[j]  = Wk0[(hh * 16 + r) * 16 + j];
    wbr[j] = wb0[(hh * 4 + (r & 3)) * 16 + j];
  }
  // -------- fln + mean prologue: wave w computes s = 4w..4w+3 ----------
  {
    const float4 g4 = ((const float4*)flng)[lane];
    const float4 b4 = ((const float4*)flnb)[lane];
    for (int k = 0; k < 4; ++k) {
      const int s = w * 4 + k;
      float a0 = 0.f, a1 = 0.f, a2 = 0.f, a3 = 0.f;
      for (int pp = 0; pp < 16; ++pp) {
        const float4 v4 = ((const float4*)(h + ((size_t)(s * cB + b) * cP + pp) * cD))[lane];
        const float s1 = wave_sum64(v4.x + v4.y + v4.z + v4.w);
        const float s2 = wave_sum64(v4.x * v4.x + v4.y * v4.y + v4.z * v4.z + v4.w * v4.w);
        const float m = s1 * (1.f / 256.f);
        const float rst = rsqrtf(s2 * (1.f / 256.f) - m * m + LEPS);
        a0 += (v4.x - m) * rst * g4.x + b4.x;
        a1 += (v4.y - m) * rst * g4.y + b4.y;
        a2 += (v4.z - m) * rst * g4.z + b4.z;
        a3 += (v4.w - m) * rst * g4.w + b4.w;
      }
      ((float4*)gmat[s])[lane] =
          make_float4(a0 * (1.f / 16.f), a1 * (1.f / 16.f),
                      a2 * (1.f / 16.f), a3 * (1.f / 16.f));
    }
  }
  // -------- projection constants: gw[c]=g_t*w_tc (regs), Gc,Bc (block) ----
  float wrow[cNC], gw[cNC];
  const float gg = lng[t], bb = lnb[t];
#pragma unroll
  for (int c = 0; c < cNC; ++c) {
    wrow[c] = outW[(size_t)t * cNC + c];
    gw[c] = gg * wrow[c];
  }
  {
#pragma unroll
    for (int c = 0; c < cNC; ++c) {
      const float pg = wave_sum64(gw[c]);
      const float pb = wave_sum64(bb * wrow[c]);
      if ((t & 63) == 0) { GBp[w][c] = pg; GBp[w][5 + c] = pb; }
    }
  }
  __syncthreads();
  if (t < 10) GBs[t] = GBp[0][t] + GBp[1][t] + GBp[2][t] + GBp[3][t];
  float xp[16];
#pragma unroll
  for (int s = 0; s < 16; ++s) xp[s] = gmat[s][t];
  __syncthreads();
  float Gc = 0.f, Bc = 0.f;
  if (t < cNC) { Gc = GBs[t]; Bc = GBs[5 + t]; }
  // ------------------------------ scan ------------------------------------
  for (int s = 0; s < cS; ++s) {
    const float xv = xp[s];
    float y = 0.f, q = 0.f, k = 0.f, bt = 0.f;
#pragma unroll
    for (int j = 0; j < 16; ++j) {
      const float xj = __shfl(xv, j, 16);
      y += wy[j] * xj; q += wq[j] * xj; k += wk[j] * xj; bt += wbr[j] * xj;
    }
    const float bsig = sigm(bt);
    const float eq = __expf(q), ek = __expf(k);
    float ay = 0.f, vyk = 0.f, vqq = 0.f, vqk = 0.f, vkq = 0.f, vkk = 0.f, vbq = 0.f, vbk = 0.f;
    float ksj[16];
#pragma unroll
    for (int j = 0; j < 16; ++j) {
      const float qj = __shfl(eq, j, 16);
      const float kj = __shfl(ek, j, 16);
      ksj[j] = kj;
      ay  += wy[j]  * qj; vyk += wy[j]  * kj;
      vqq += wq[j]  * qj; vqk += wq[j]  * kj;
      vkq += wk[j]  * qj; vkk += wk[j]  * kj;
      vbq += wbr[j] * qj; vbk += wbr[j] * kj;
    }
    const float rq = frcp(row_sum16(eq));
    const float rk = frcp(row_sum16(ek));
    const float ea = __expf(ay * rq);
    const float vyq = ea * frcp(row_sum16(ea));
    const float b0  = __shfl(bsig, 0, 16);
    const float b1v = __shfl(bsig, 1, 16);
    const float b2v = __shfl(bsig, 2, 16);
    const float b3v = __shfl(bsig, 3, 16);
    const float cy = b0  * (vyq      - vyk * rk) * rk;
    const float cq = b1v * (vqq * rq - vqk * rk) * rk;
    const float ck = b2v * (vkq * rq - vkk * rk) * rk;
    const float cb = b3v * (vbq * rq - vbk * rk) * rk;
#pragma unroll
    for (int j = 0; j < 16; ++j) {
      wy[j] += cy * ksj[j]; wq[j] += cq * ksj[j]; wk[j] += ck * ksj[j]; wbr[j] += cb * ksj[j];
    }
    // single barrier: LN stats + projection partials together
    const float s1 = wave_sum64(y);
    const float s2 = wave_sum64(y * y);
    float S1[cNC];
#pragma unroll
    for (int c = 0; c < cNC; ++c) S1[c] = wave_sum64(y * gw[c]);
    const int db = s & 1;
    if ((t & 63) == 0) {
      PR[db][w][0] = s1; PR[db][w][1] = s2;
#pragma unroll
      for (int c = 0; c < cNC; ++c) PR[db][w][2 + c] = S1[c];
    }
    __syncthreads();
    if (t < cNC) {
      const float sm1 = PR[db][0][0] + PR[db][1][0] + PR[db][2][0] + PR[db][3][0];
      const float sm2 = PR[db][0][1] + PR[db][1][1] + PR[db][2][1] + PR[db][3][1];
      const float Sc  = PR[db][0][2 + t] + PR[db][1][2 + t] + PR[db][2][2 + t] + PR[db][3][2 + t];
      const float m = sm1 * (1.f / 256.f);
      const float var = sm2 * (1.f / 256.f) - m * m;
      const float rst = rsqrtf(var + LEPS);
      outp[(size_t)(s * cB + b) * cNC + t] = outb[t] + rst * Sc - rst * m * Gc + Bc;
    }
  }
}

extern "C" void kernel_launch(void* const* d_in, const int* in_sizes, int n_in,
                              void* d_out, int out_size, void* d_ws, size_t ws_size,
                              hipStream_t stream) {
  const float* x     = (const float*)d_in[0];
  const int*   fb    = (const int*)d_in[1];
  const float* inW   = (const float*)d_in[2];
  const float* inb   = (const float*)d_in[3];
  const float* tkWy  = (const float*)d_in[4];
  const float* tkWq  = (const float*)d_in[5];
  const float* tkWk  = (const float*)d_in[6];
  const float* tkwb  = (const float*)d_in[7];
  const float* tklng = (const float*)d_in[8];
  const float* tklnb = (const float*)d_in[9];
  const float* tkmg  = (const float*)d_in[10];
  const float* tkmb  = (const float*)d_in[11];
  const float* tkmW1 = (const float*)d_in[12];
  const float* tkmb1 = (const float*)d_in[13];
  const float* tkmW2 = (const float*)d_in[14];
  const float* tkmb2 = (const float*)d_in[15];
  const float* chWy  = (const float*)d_in[16];
  const float* chWq  = (const float*)d_in[17];
  const float* chWk  = (const float*)d_in[18];
  const float* chwb  = (const float*)d_in[19];
  const float* chlng = (const float*)d_in[20];
  const float* chlnb = (const float*)d_in[21];
  const float* chmg  = (const float*)d_in[22];
  const float* chmb  = (const float*)d_in[23];
  const float* chmW1 = (const float*)d_in[24];
  const float* chmb1 = (const float*)d_in[25];
  const float* chmW2 = (const float*)d_in[26];
  const float* chmb2 = (const float*)d_in[27];
  const float* flng  = (const float*)d_in[28];
  const float* flnb  = (const float*)d_in[29];
  const float* oWy   = (const float*)d_in[30];
  const float* oWq   = (const float*)d_in[31];
  const float* oWk   = (const float*)d_in[32];
  const float* owb   = (const float*)d_in[33];
  const float* olng  = (const float*)d_in[34];
  const float* olnb  = (const float*)d_in[35];
  const float* outW  = (const float*)d_in[36];
  const float* outb  = (const float*)d_in[37];

  float* h    = (float*)d_ws;                               // (S,B,P,D) fp32 = 2 MB
  float* outp = (float*)d_out;                              // (S,B,NC) fp32

  for (int i = 0; i < 2; ++i) {
    k_tok_srwm<<<dim3(128), dim3(256), 0, stream>>>(
        h, tkWy + i * 256, tkWq + i * 256, tkWk + i * 256, tkwb + i * 64,
        tklng + i * 16, tklnb + i * 16,
        (i == 0) ? 1 : 0, x, fb, inW, inb);
    k_tok_mixer<<<dim3(cS * cB), dim3(256), 0, stream>>>(
        h, tkmg + i * 256, tkmb + i * 256, tkmW1 + i * 1024, tkmb1 + i * 64,
        tkmW2 + i * 1024, tkmb2 + i * 16);
    k_ch_srwm_mix<<<dim3(cB * cP), dim3(256), 0, stream>>>(
        h, chWy + i * 4096, chWq + i * 4096, chWk + i * 4096, chwb + i * 1024,
        chlng + i * 256, chlnb + i * 256,
        chmg + i * 256, chmb + i * 256, chmW1 + i * 32768, chmb1 + i * 128,
        chmW2 + i * 32768, chmb2 + i * 256);
  }
  k_out_srwm<<<dim3(cB), dim3(256), 0, stream>>>(
      h, outp, flng, flnb, oWy, oWq, oWk, owb, olng, olnb, outW, outb);
}